// Round 18
// baseline (45.989 us; speedup 1.0000x reference)
//
#include <hip/hip_runtime.h>
#include <math.h>

// E8S codebook quantization via 16x16x32 bf16 MFMA, exact 3-way split.
//   scores[r][c] = 2*X[r]·G[c] - ||G[c]||^2 ; idx = first-argmax over c.
// K=32 = 4 groups of 8 (kg=lane>>4): {h,m,l,0} x coords. Bias -gn enters as
// the MFMA C OPERAND (f32, per-slot) -> kg3 B-slice is zeros and every lane
// reads the SAME coords slice (broadcast). D layout: col=lane&15 (row),
// cw_in_tile = kg*4 + reg (validated R4-R17, absmax 0).
// R18: A-fragments staged through LDS (R8-R17 were L2 same-line-hotspot bound:
// 16 KB/CU of identical G data per 310-cyc round; R14's LDS try died on a
// 4-way bank conflict from its 32x16B pattern). Here the A-read is 16 unique
// 16B (2-way = free) + 64B C-table (conflict-free). 8-tile batches, double
// buffered, loads issued before the compute asm, ds_read 2-deep lgkmcnt(2).
// Mega-asm fixed regs: v24-27 bs | v28-31 bi | v40 Aaddr v41 Caddr |
// v44-51 A dbuf | v52-59 C dbuf | v60-75 B (4 row-tiles) | v76-91 dA |
// v92-107 dB | v108-123 dm. Group=8 tiles -> tree + (score,group) track;
// u64 atomicMax(enc_ord<<32|~gid). Resolve rescans the winning group's 8
// tiles bit-identically (same A,B,C bytes, same instruction), ascending ->
// np.argmax first-max (validated R11/R16/R17).

typedef short short8 __attribute__((ext_vector_type(8)));
typedef float f32x4  __attribute__((ext_vector_type(4)));
typedef unsigned int u32x4 __attribute__((ext_vector_type(4)));

constexpr int NROWS  = 8192;
constexpr int NCW    = 55650;
constexpr int NT16   = 3488;          // 16-codeword tiles
constexpr int NG     = 436;           // 8-tile groups (128 cw each)
constexpr int NCWP2  = NT16 * 16;     // 55808
constexpr int NCHUNK = 32;            // group chunks (grid.y)
constexpr int RBLK   = 32;            // row blocks of 256 rows (grid.x)

// Gb global layout: per tile 320B = [16 cw x 16B coords | 16 x f32 (-gn)]
constexpr size_t OFF_GB = 0;                              // NT16*320 B
constexpr size_t OFF_XS = OFF_GB + (size_t)NT16 * 320;    // ushort Xs[NROWS*32]
constexpr size_t OFF_BK = OFF_XS + (size_t)NROWS * 64;    // u64 best[NROWS]

__device__ inline unsigned short bf16_rne(float f) {
  unsigned int u = __float_as_uint(f);
  unsigned int r = u + 0x7FFFu + ((u >> 16) & 1u);
  return (unsigned short)(r >> 16);
}
__device__ inline float bf16_f(unsigned short h) {
  return __uint_as_float(((unsigned int)h) << 16);
}
__device__ inline unsigned int enc_ord(float f) {
  unsigned int u = __float_as_uint(f);
  return (u & 0x80000000u) ? ~u : (u | 0x80000000u);
}
__device__ inline float dec_ord(unsigned int e) {
  unsigned int u = (e & 0x80000000u) ? (e & 0x7FFFFFFFu) : ~e;
  return __uint_as_float(u);
}

__global__ __launch_bounds__(256) void e8_prep(
    const float* __restrict__ X, const float* __restrict__ G,
    const float* __restrict__ GN, unsigned char* __restrict__ GbB,
    unsigned short* __restrict__ Xs, unsigned long long* __restrict__ best) {
  int i = blockIdx.x * 256 + threadIdx.x;
  if (i < NCWP2) {
    unsigned char* gt = GbB + (size_t)(i >> 4) * 320;
    unsigned short c8[8];
    float cgn;
    if (i < NCW) {
      for (int j = 0; j < 8; ++j) c8[j] = bf16_rne(G[(size_t)i*8+j]);
      cgn = -GN[i];
    } else {
      for (int j = 0; j < 8; ++j) c8[j] = 0;
      cgn = -3.0e38f;                   // pad: score can never win
    }
    *reinterpret_cast<u32x4*>(gt + (size_t)(i & 15) * 16) =
        *reinterpret_cast<u32x4*>(c8);
    *reinterpret_cast<float*>(gt + 256 + (size_t)(i & 15) * 4) = cgn;
  } else if (i < NCWP2 + NROWS) {
    int r = i - NCWP2;
    unsigned short hh[8], mm[8], ll[8], qq[8];
    for (int j = 0; j < 8; ++j) {
      float s = 2.0f * X[(size_t)r*8+j];           // exact
      unsigned short h = bf16_rne(s);  float r1 = s  - bf16_f(h);  // exact
      unsigned short m = bf16_rne(r1); float r2 = r1 - bf16_f(m);  // exact
      unsigned short l = bf16_rne(r2);             // residual after 3 terms = 0
      hh[j] = h; mm[j] = m; ll[j] = l; qq[j] = 0;  // slice 3 = zeros
    }
    u32x4* dst = reinterpret_cast<u32x4*>(Xs + (size_t)r * 32);
    dst[0] = *reinterpret_cast<u32x4*>(hh);
    dst[1] = *reinterpret_cast<u32x4*>(mm);
    dst[2] = *reinterpret_cast<u32x4*>(ll);
    dst[3] = *reinterpret_cast<u32x4*>(qq);
    best[r] = 0ull;
  }
}

// ---- mega-asm building blocks ---------------------------------------------
#define MV(d, s) "v_mov_b32 v" #d ", v" #s "\n\t"
#define MX(d, s) "v_max_f32 v" #d ", v" #d ", v" #s "\n\t"

// even tile: dA (v76-91), A buf v44-47, C buf v52-55; prefetch t+2 at off P.
#define TE(P) \
  "s_waitcnt lgkmcnt(2)\n\t" \
  "v_mfma_f32_16x16x32_bf16 v[76:79], v[44:47], v[60:63], v[52:55]\n\t" \
  "v_mfma_f32_16x16x32_bf16 v[80:83], v[44:47], v[64:67], v[52:55]\n\t" \
  "v_mfma_f32_16x16x32_bf16 v[84:87], v[44:47], v[68:71], v[52:55]\n\t" \
  "v_mfma_f32_16x16x32_bf16 v[88:91], v[44:47], v[72:75], v[52:55]\n\t" \
  "ds_read_b128 v[44:47], v40 offset:" P "\n\t" \
  "ds_read_b128 v[52:55], v41 offset:" P "\n\t"

// odd tile: dB (v92-107), A buf v48-51, C buf v56-59.
#define TO(P) \
  "s_waitcnt lgkmcnt(2)\n\t" \
  "v_mfma_f32_16x16x32_bf16 v[92:95],   v[48:51], v[60:63], v[56:59]\n\t" \
  "v_mfma_f32_16x16x32_bf16 v[96:99],   v[48:51], v[64:67], v[56:59]\n\t" \
  "v_mfma_f32_16x16x32_bf16 v[100:103], v[48:51], v[68:71], v[56:59]\n\t" \
  "v_mfma_f32_16x16x32_bf16 v[104:107], v[48:51], v[72:75], v[56:59]\n\t" \
  "ds_read_b128 v[48:51], v40 offset:" P "\n\t" \
  "ds_read_b128 v[56:59], v41 offset:" P "\n\t"

#define MOV16 \
  MV(108,76) MV(109,77) MV(110,78) MV(111,79) MV(112,80) MV(113,81) \
  MV(114,82) MV(115,83) MV(116,84) MV(117,85) MV(118,86) MV(119,87) \
  MV(120,88) MV(121,89) MV(122,90) MV(123,91)

#define MAXA16 \
  MX(108,76) MX(109,77) MX(110,78) MX(111,79) MX(112,80) MX(113,81) \
  MX(114,82) MX(115,83) MX(116,84) MX(117,85) MX(118,86) MX(119,87) \
  MX(120,88) MX(121,89) MX(122,90) MX(123,91)

#define MAXB16 \
  MX(108,92)  MX(109,93)  MX(110,94)  MX(111,95)  MX(112,96)  MX(113,97) \
  MX(114,98)  MX(115,99)  MX(116,100) MX(117,101) MX(118,102) MX(119,103) \
  MX(120,104) MX(121,105) MX(122,106) MX(123,107)

#define TREE \
  MX(108,109) MX(110,111) MX(112,113) MX(114,115) \
  MX(116,117) MX(118,119) MX(120,121) MX(122,123) \
  MX(108,110) MX(112,114) MX(116,118) MX(120,122)

#define TRACK \
  "v_cmp_gt_f32 vcc, v108, v24\n\t" \
  "v_cndmask_b32 v28, v28, %[gi], vcc\n\t" \
  "v_max_f32 v24, v24, v108\n\t" \
  "v_cmp_gt_f32 vcc, v112, v25\n\t" \
  "v_cndmask_b32 v29, v29, %[gi], vcc\n\t" \
  "v_max_f32 v25, v25, v112\n\t" \
  "v_cmp_gt_f32 vcc, v116, v26\n\t" \
  "v_cndmask_b32 v30, v30, %[gi], vcc\n\t" \
  "v_max_f32 v26, v26, v116\n\t" \
  "v_cmp_gt_f32 vcc, v120, v27\n\t" \
  "v_cndmask_b32 v31, v31, %[gi], vcc\n\t" \
  "v_max_f32 v27, v27, v120\n\t"

// one 8-tile group from LDS (tiles at 320B stride from v40/v41 bases).
#define BATCH8 \
  "v_mov_b32 v40, %[la]\n\t" \
  "v_mov_b32 v41, %[lc]\n\t" \
  "ds_read_b128 v[44:47], v40\n\t" \
  "ds_read_b128 v[52:55], v41\n\t" \
  "ds_read_b128 v[48:51], v40 offset:320\n\t" \
  "ds_read_b128 v[56:59], v41 offset:320\n\t" \
  TE("640") TO("960") MOV16 \
  TE("1280") MAXB16 TO("1600") MAXA16 \
  TE("1920") MAXB16 TO("2240") MAXA16 \
  TE("2560") MAXB16 TO("2880") MAXA16 \
  "s_nop 7\n\t" "s_nop 7\n\t" \
  MAXB16 TREE TRACK "s_nop 0"

#define CLOBS \
  "v24","v25","v26","v27","v28","v29","v30","v31", \
  "v40","v41","v42","v43","v44","v45","v46","v47","v48","v49", \
  "v50","v51","v52","v53","v54","v55","v56","v57","v58","v59", \
  "v60","v61","v62","v63","v64","v65","v66","v67","v68","v69", \
  "v70","v71","v72","v73","v74","v75","v76","v77","v78","v79", \
  "v80","v81","v82","v83","v84","v85","v86","v87","v88","v89", \
  "v90","v91","v92","v93","v94","v95","v96","v97","v98","v99", \
  "v100","v101","v102","v103","v104","v105","v106","v107","v108","v109", \
  "v110","v111","v112","v113","v114","v115","v116","v117","v118","v119", \
  "v120","v121","v122","v123"

// Per block: 4 waves x 4 row-tiles = 256 rows, chunk of 13-14 groups.
// Grid 32x32 = 1024 blocks = 4 blocks/CU = 4 waves/SIMD (VGPR <= 128).
__global__ __launch_bounds__(256, 4) void e8_main(
    const unsigned char* __restrict__ GbB,
    const unsigned short* __restrict__ Xs,
    unsigned long long* __restrict__ best) {
  const int tid  = threadIdx.x;
  const int lane = tid & 63;
  const int wave = tid >> 6;
  const int l15 = lane & 15, kg = lane >> 4;
  const int rowbase = blockIdx.x * 256 + wave * 64;

  __shared__ char smem[6912];           // 2 x 3328B buffers (+ overrun pad)
  ((volatile char*)smem)[tid] = 0;      // force LDS alloc + M0 init

  const int g0 = blockIdx.y * NG / NCHUNK;
  const int g1 = (blockIdx.y + 1) * NG / NCHUNK;
  const unsigned long long xsv = (unsigned long long)Xs;

  const unsigned bvo = (unsigned)(rowbase + l15) * 64u + (unsigned)kg * 16u;

  // prologue: bs=-inf, bi=0, load 4 B-frags (row-tiles 0..3), drain.
  asm volatile(
      "v_mov_b32 v24, 0xff800000\n\t" "v_mov_b32 v25, 0xff800000\n\t"
      "v_mov_b32 v26, 0xff800000\n\t" "v_mov_b32 v27, 0xff800000\n\t"
      "v_mov_b32 v28, 0\n\t" "v_mov_b32 v29, 0\n\t"
      "v_mov_b32 v30, 0\n\t" "v_mov_b32 v31, 0\n\t"
      "global_load_dwordx4 v[60:63], %[bo], %[xs]\n\t"
      "global_load_dwordx4 v[64:67], %[bo], %[xs] offset:1024\n\t"
      "global_load_dwordx4 v[68:71], %[bo], %[xs] offset:2048\n\t"
      "global_load_dwordx4 v[72:75], %[bo], %[xs] offset:3072\n\t"
      "s_waitcnt vmcnt(0)"
      :: [xs]"s"(xsv), [bo]"v"(bvo)
      : CLOBS, "memory");

  // initial stage: group g0 -> buffer 0 (80 threads x 32B = 2560B)
  if (tid < 80) {
    const u32x4* s = reinterpret_cast<const u32x4*>(
        GbB + (size_t)g0 * 2560 + (size_t)tid * 32);
    u32x4 a = s[0], b2 = s[1];
    unsigned doff = (unsigned)tid * 32u;
    asm volatile(
        "ds_write_b128 %[ad], %[v0]\n\t"
        "ds_write_b128 %[ad], %[v1] offset:16"
        :: [ad]"v"(doff), [v0]"v"(a), [v1]"v"(b2) : "memory");
  }
  __syncthreads();

  for (int g = g0; g < g1; ++g) {
    const int gnx = g + 1;
    const bool do_stage = (gnx < g1) && (tid < 80);
    u32x4 va = {0,0,0,0}, vb2 = {0,0,0,0};
    if (do_stage) {                     // issue next group's loads NOW (T14)
      const u32x4* s = reinterpret_cast<const u32x4*>(
          GbB + (size_t)gnx * 2560 + (size_t)tid * 32);
      va = s[0]; vb2 = s[1];
    }

    const unsigned par = (unsigned)((g - g0) & 1) * 3328u;
    const unsigned la = par + (unsigned)l15 * 16u;
    const unsigned lc = par + 256u + (unsigned)kg * 16u;
    asm volatile(BATCH8
        :: [la]"v"(la), [lc]"v"(lc), [gi]"v"(g)
        : CLOBS, "vcc", "memory");

    if (do_stage) {                     // write next group into other buffer
      const unsigned doff =
          (unsigned)((gnx - g0) & 1) * 3328u + (unsigned)tid * 32u;
      asm volatile(
          "ds_write_b128 %[ad], %[v0]\n\t"
          "ds_write_b128 %[ad], %[v1] offset:16"
          :: [ad]"v"(doff), [v0]"v"(va), [v1]"v"(vb2) : "memory");
    }
    __syncthreads();
  }

  float bs0, bs1, bs2, bs3; int bi0, bi1, bi2, bi3;
  asm volatile(
      "s_waitcnt vmcnt(0) lgkmcnt(0)\n\t"
      "v_mov_b32 %0, v24\n\t" "v_mov_b32 %1, v25\n\t"
      "v_mov_b32 %2, v26\n\t" "v_mov_b32 %3, v27\n\t"
      "v_mov_b32 %4, v28\n\t" "v_mov_b32 %5, v29\n\t"
      "v_mov_b32 %6, v30\n\t" "v_mov_b32 %7, v31"
      : "=v"(bs0), "=v"(bs1), "=v"(bs2), "=v"(bs3),
        "=v"(bi0), "=v"(bi1), "=v"(bi2), "=v"(bi3) :: "memory");

  const float bsa[4] = {bs0, bs1, bs2, bs3};
  const int   bia[4] = {bi0, bi1, bi2, bi3};
#pragma unroll
  for (int t = 0; t < 4; ++t) {
    unsigned long long key =
        ((unsigned long long)enc_ord(bsa[t]) << 32) | (unsigned int)(~bia[t]);
    unsigned long long o = __shfl_xor(key, 16, 64);
    key = (o > key) ? o : key;          // merge the 4 kg quads of a row
    o = __shfl_xor(key, 32, 64);
    key = (o > key) ? o : key;
    if (lane < 16)
      atomicMax(&best[(size_t)rowbase + t * 16 + l15], key);
  }
}

// 512 blocks x 4 waves; block = one 16-row tile, wave handles 4 rows:
// re-run the bit-identical MFMA over the winning GROUP's 8 tiles, take the
// smallest matching global index, write vals + idx.
__global__ __launch_bounds__(256) void e8_resolve(
    const unsigned char* __restrict__ GbB,
    const unsigned short* __restrict__ Xs, const float* __restrict__ G,
    const unsigned long long* __restrict__ best, float* __restrict__ out) {
  const int lane = threadIdx.x & 63;
  const int wave = threadIdx.x >> 6;
  const int l15 = lane & 15, kg = lane >> 4;
  const int rt = blockIdx.x;              // 0..511 (16-row tile)

  short8 b;
  {
    const size_t row = (size_t)rt * 16 + l15;
    b = *reinterpret_cast<const short8*>(Xs + (row*4 + kg)*8);
  }

  for (int j = wave * 4; j < wave * 4 + 4; ++j) {
    const int srow = rt * 16 + j;
    const unsigned long long k = best[srow];
    const float sstar = dec_ord((unsigned int)(k >> 32));
    const int gwin = (int)(~(unsigned int)(k & 0xFFFFFFFFull));

    const int tb = gwin * 8;
    int cand = 0x7FFFFFFF;
    for (int tt = tb; tt < tb + 8; ++tt) {
      const unsigned char* gt = GbB + (size_t)tt * 320;
      short8 a = *reinterpret_cast<const short8*>(gt + (size_t)l15 * 16);
      f32x4 C = *reinterpret_cast<const f32x4*>(gt + 256 + (size_t)kg * 16);
      f32x4 d = __builtin_amdgcn_mfma_f32_16x16x32_bf16(a, b, C, 0, 0, 0);

      int tc = 0x0FFFFFFF;
#pragma unroll
      for (int r = 3; r >= 0; --r)      // descending -> smallest slot wins
        tc = (d[r] == sstar) ? r : tc;
      const int gidx = tt * 16 + kg * 4 + tc;   // huge if no match
      cand = (gidx < cand) ? gidx : cand;       // tiles ascend -> first match
    }
    if (l15 != j) cand = 0x7FFFFFFF;    // only this row's 4 lanes count
    int o = __shfl_xor(cand, 16, 64); cand = min(cand, o);
    o = __shfl_xor(cand, 32, 64);     cand = min(cand, o);
    if (lane == j) {
      const float4* g = reinterpret_cast<const float4*>(G + (size_t)cand * 8);
      float4 v0 = g[0], v1 = g[1];
      float4* od = reinterpret_cast<float4*>(out + (size_t)srow * 8);
      od[0] = v0; od[1] = v1;
      out[(size_t)NROWS * 8 + srow] = (float)(cand - 32768);
    }
  }
}

extern "C" void kernel_launch(void* const* d_in, const int* in_sizes, int n_in,
                              void* d_out, int out_size, void* d_ws, size_t ws_size,
                              hipStream_t stream) {
  const float* X  = (const float*)d_in[0];
  const float* G  = (const float*)d_in[1];
  const float* GN = (const float*)d_in[2];
  float* out = (float*)d_out;

  char* ws = (char*)d_ws;
  unsigned char*      GbB  = (unsigned char*)(ws + OFF_GB);
  unsigned short*     Xs   = (unsigned short*)(ws + OFF_XS);
  unsigned long long* best = (unsigned long long*)(ws + OFF_BK);

  e8_prep<<<(NCWP2 + NROWS + 255) / 256, 256, 0, stream>>>(X, G, GN, GbB, Xs, best);
  e8_main<<<dim3(RBLK, NCHUNK), 256, 0, stream>>>(GbB, Xs, best);
  e8_resolve<<<512, 256, 0, stream>>>(GbB, Xs, G, best, out);
}